// Round 6
// baseline (796.562 us; speedup 1.0000x reference)
//
#include <hip/hip_runtime.h>
#include <hip/hip_bf16.h>

// Problem constants
#define H_ 8
#define D_ 512
#define DK_ 64
#define B_ 16
#define N_ 8192
#define M_ (B_ * N_)  // 131072 rows

typedef __attribute__((ext_vector_type(8))) short short8;
typedef __attribute__((ext_vector_type(4))) float floatx4;

// ---------------------------------------------------------------- helpers
// pack two fp32 -> two bf16 (round-half-up): low16 = bf(x), high16 = bf(y)
__device__ __forceinline__ unsigned pack_bf2(float x, float y) {
    return __builtin_amdgcn_perm(__float_as_uint(y) + 0x8000u,
                                 __float_as_uint(x) + 0x8000u, 0x07060302u);
}

__device__ __forceinline__ short8 pack_bf8(float4 lo, float4 hi) {
    union { unsigned u[4]; short8 s; } tmp;
    tmp.u[0] = pack_bf2(lo.x, lo.y);
    tmp.u[1] = pack_bf2(lo.z, lo.w);
    tmp.u[2] = pack_bf2(hi.x, hi.y);
    tmp.u[3] = pack_bf2(hi.z, hi.w);
    return tmp.s;
}

// ---------------------------------------------------------------- kernel 1: W-stationary fused double-GEMM + gate + query-dot
// Block = (head h, 256-row m-chunk). 4 waves x 64 rows each, covering the
// head's full 64 dk-cols for BOTH gemms. W_k[h]/W_g[h] staged in LDS per
// 256-wide K-phase (2 phases, 2 barrier pairs TOTAL — no barriers in the
// K-loop). A fragments load fp32 straight from global (L2-served via XCD
// remap), pack to bf16 in regs. LDS rows padded to 33 chunks (528 B) ->
// bank-optimal b128 reads (2-way over 16 lanes) and writes (8x8 uniform).
__global__ __launch_bounds__(256, 2) void gemm_score_kernel(
    const float* __restrict__ x,       // (M_, 512) fp32
    const float* __restrict__ Wk,      // (512, 512) fp32
    const float* __restrict__ Wg,      // (512, 512) fp32
    const float* __restrict__ query,   // (8, 64) fp32
    float* __restrict__ s_buf)         // (B_, H_, N_) fp32
{
    // [gemm][64 dk-rows][264 ushorts] : row stride 264 (33 x 16B chunks)
    __shared__ unsigned short ldsW[2][64 * 264];  // 2 x 33792 B = 67584 B

    const int t = threadIdx.x;
    const int lane = t & 63;
    const int wave = t >> 6;

    // XCD remap: the 8 head-siblings of one m-chunk land on one XCD (ids 8 apart)
    const int g = blockIdx.x;              // 0..4095
    const int xcd = g & 7;
    const int s = g >> 3;                  // 0..511
    const int h = s & 7;                   // head
    const int mc = ((s >> 3) << 3) | xcd;  // 0..511
    const int m0 = mc * 256;

    floatx4 acc_k[4][4], acc_g[4][4];
#pragma unroll
    for (int i = 0; i < 4; ++i)
#pragma unroll
        for (int j = 0; j < 4; ++j) { acc_k[i][j] = (floatx4)0.f; acc_g[i][j] = (floatx4)0.f; }

    const int fr = lane & 15;   // A-row / B-col within 16-tile
    const int q  = lane >> 4;   // k-quarter (8 elems)

    // A bases: wave owns rows m0 + wave*64 + mi*16 + fr; lane k-offset q*8
    const float* pA[4];
#pragma unroll
    for (int mi = 0; mi < 4; ++mi)
        pA[mi] = x + (size_t)(m0 + wave * 64 + mi * 16 + fr) * 512 + q * 8;

    // B lane bases (ushort index into a gemm's LDS plane)
    int bo[4];
#pragma unroll
    for (int ni = 0; ni < 4; ++ni) bo[ni] = (ni * 16 + fr) * 264 + q * 8;

    // W staging source bases
    const float* wkRow = Wk + (size_t)h * 64 * 512;
    const float* wgRow = Wg + (size_t)h * 64 * 512;

    for (int ph = 0; ph < 2; ++ph) {
        if (ph) __syncthreads();  // all reads of previous half done
        // ---- stage W half: 64 rows x 32 bf16-chunks per gemm; thread t -> 8 chunks/gemm
#pragma unroll
        for (int i = 0; i < 8; ++i) {
            int j = i * 256 + t;
            int row = j >> 5, c8 = j & 31;           // c8: 8-bf16 chunk
            size_t so = (size_t)row * 512 + ph * 256 + c8 * 8;
            float4 k0 = *(const float4*)(wkRow + so);
            float4 k1 = *(const float4*)(wkRow + so + 4);
            float4 g0 = *(const float4*)(wgRow + so);
            float4 g1 = *(const float4*)(wgRow + so + 4);
            *(short8*)&ldsW[0][row * 264 + c8 * 8] = pack_bf8(k0, k1);
            *(short8*)&ldsW[1][row * 264 + c8 * 8] = pack_bf8(g0, g1);
        }
        __syncthreads();

        const int kb = ph * 256;  // fp32 k offset
        // ---- barrier-free K-loop: 8 x K=32
#pragma unroll
        for (int kt = 0; kt < 8; ++kt) {
            short8 a[4], bk[4], bg[4];
#pragma unroll
            for (int mi = 0; mi < 4; ++mi) {
                float4 f0 = *(const float4*)(pA[mi] + kb + kt * 32);
                float4 f1 = *(const float4*)(pA[mi] + kb + kt * 32 + 4);
                a[mi] = pack_bf8(f0, f1);
            }
#pragma unroll
            for (int ni = 0; ni < 4; ++ni) {
                bk[ni] = *(const short8*)&ldsW[0][bo[ni] + kt * 32];
                bg[ni] = *(const short8*)&ldsW[1][bo[ni] + kt * 32];
            }
#pragma unroll
            for (int mi = 0; mi < 4; ++mi)
#pragma unroll
                for (int ni = 0; ni < 4; ++ni) {
                    acc_k[mi][ni] = __builtin_amdgcn_mfma_f32_16x16x32_bf16(a[mi], bk[ni], acc_k[mi][ni], 0, 0, 0);
                    acc_g[mi][ni] = __builtin_amdgcn_mfma_f32_16x16x32_bf16(a[mi], bg[ni], acc_g[mi][ni], 0, 0, 0);
                }
        }
    }

    // Epilogue: gated = tanh(K)*sigmoid(G); score = q . gated over all 64 dk.
    // C/D layout: col = lane&15 (dk), row = q*4 + reg (m). Waves own disjoint rows.
    float qv[4];
#pragma unroll
    for (int ni = 0; ni < 4; ++ni) qv[ni] = query[h * 64 + ni * 16 + fr];

#pragma unroll
    for (int mi = 0; mi < 4; ++mi) {
#pragma unroll
        for (int r = 0; r < 4; ++r) {
            float v = 0.f;
#pragma unroll
            for (int ni = 0; ni < 4; ++ni) {
                float kv = acc_k[mi][ni][r];
                float gv = acc_g[mi][ni][r];
                float e2k = __expf(2.f * kv);
                float th = 1.f - 2.f / (e2k + 1.f);       // tanh, overflow-safe
                float sg = 1.f / (1.f + __expf(-gv));     // sigmoid
                v += qv[ni] * th * sg;
            }
            v += __shfl_xor(v, 1);
            v += __shfl_xor(v, 2);
            v += __shfl_xor(v, 4);
            v += __shfl_xor(v, 8);
            if (fr == 0) {
                int mg = m0 + wave * 64 + mi * 16 + q * 4 + r;
                int b = mg >> 13, n = mg & 8191;
                s_buf[((size_t)(b * 8 + h) << 13) + n] = v;
            }
        }
    }
}

// ---------------------------------------------------------------- kernel 2: per-(b,h) softmax stats
__global__ __launch_bounds__(256) void stats_kernel(const float* __restrict__ s_buf,
                                                    float* __restrict__ mb, float* __restrict__ lb) {
    const int bh = blockIdx.x;  // 0..127
    const float* s = s_buf + ((size_t)bh << 13);
    const int t = threadIdx.x;
    float mx = -3.0e38f;
    for (int i = t; i < 8192; i += 256) mx = fmaxf(mx, s[i]);
#pragma unroll
    for (int m = 32; m > 0; m >>= 1) mx = fmaxf(mx, __shfl_xor(mx, m));
    __shared__ float red[8];
    if ((t & 63) == 0) red[t >> 6] = mx;
    __syncthreads();
    mx = fmaxf(fmaxf(red[0], red[1]), fmaxf(red[2], red[3]));
    float sum = 0.f;
    for (int i = t; i < 8192; i += 256) sum += __expf(s[i] - mx);
#pragma unroll
    for (int m = 32; m > 0; m >>= 1) sum += __shfl_xor(sum, m);
    if ((t & 63) == 0) red[4 + (t >> 6)] = sum;
    __syncthreads();
    if (t == 0) { mb[bh] = mx; lb[bh] = red[4] + red[5] + red[6] + red[7]; }
}

// ---------------------------------------------------------------- kernel 3a: partial weighted sums (no atomics)
__global__ __launch_bounds__(256) void out_part_kernel(
    const float* __restrict__ x, const float* __restrict__ s_buf,
    const float* __restrict__ mb, const float* __restrict__ lb,
    float* __restrict__ part) {
    const int b = blockIdx.x >> 5;      // 16
    const int chunk = blockIdx.x & 31;  // 32 chunks of 256 rows
    const int n0 = chunk * 256;
    const int t = threadIdx.x;
    __shared__ float w[8 * 256];
    for (int i = t; i < 2048; i += 256) {
        int hh = i >> 8, nn = i & 255;
        int bh = b * 8 + hh;
        w[i] = __expf(s_buf[((size_t)bh << 13) + n0 + nn] - mb[bh]) / lb[bh];
    }
    __syncthreads();
    const int rg = t >> 6;            // 4 row-groups (disjoint rows)
    const int d0 = (t & 63) * 8;      // 8 fp32 per thread -> full 512-wide row per wave
    const float* wh = w + ((d0 >> 6) << 8);
    float acc[8] = {0.f, 0.f, 0.f, 0.f, 0.f, 0.f, 0.f, 0.f};
    for (int nn = rg; nn < 256; nn += 4) {
        const float4* row = (const float4*)(x + (((size_t)(b * 8192 + n0 + nn)) << 9) + d0);
        float4 v0 = row[0];
        float4 v1 = row[1];
        float ww = wh[nn];
        acc[0] += ww * v0.x; acc[1] += ww * v0.y;
        acc[2] += ww * v0.z; acc[3] += ww * v0.w;
        acc[4] += ww * v1.x; acc[5] += ww * v1.y;
        acc[6] += ww * v1.z; acc[7] += ww * v1.w;
    }
    float* dst = part + ((size_t)(blockIdx.x * 4 + rg)) * 512 + d0;
    *(float4*)(dst)     = make_float4(acc[0], acc[1], acc[2], acc[3]);
    *(float4*)(dst + 4) = make_float4(acc[4], acc[5], acc[6], acc[7]);
}

// ---------------------------------------------------------------- kernel 3b: reduce partials -> out
__global__ __launch_bounds__(512) void out_reduce_kernel(const float* __restrict__ part,
                                                         float* __restrict__ out) {
    const int b = blockIdx.x;   // 16
    const int d = threadIdx.x;  // 512
    float s = 0.f;
    const float* p = part + (size_t)b * 128 * 512 + d;
    for (int i = 0; i < 128; ++i) s += p[(size_t)i * 512];
    out[b * 512 + d] = s;
}

// ---------------------------------------------------------------- launch
extern "C" void kernel_launch(void* const* d_in, const int* in_sizes, int n_in,
                              void* d_out, int out_size, void* d_ws, size_t ws_size,
                              hipStream_t stream) {
    const float* x  = (const float*)d_in[0];
    const float* Wk = (const float*)d_in[1];
    const float* Wg = (const float*)d_in[2];
    const float* q  = (const float*)d_in[3];
    float* out = (float*)d_out;

    // ws layout (~8.4 MB)
    char* ws = (char*)d_ws;
    float* s_buf = (float*)ws;                    // 4194304 B
    float* part  = (float*)(ws + 4194304ull);     // 4194304 B
    float* mb = (float*)(ws + 8388608ull);        // 512 B
    float* lb = (float*)(ws + 8389120ull);        // 512 B

    hipLaunchKernelGGL(gemm_score_kernel, dim3(4096), dim3(256), 0, stream, x, Wk, Wg, q, s_buf);
    hipLaunchKernelGGL(stats_kernel, dim3(128), dim3(256), 0, stream, s_buf, mb, lb);
    hipLaunchKernelGGL(out_part_kernel, dim3(512), dim3(256), 0, stream, x, s_buf, mb, lb, part);
    hipLaunchKernelGGL(out_reduce_kernel, dim3(16), dim3(512), 0, stream, part, out);
}

// Round 7
// 650.301 us; speedup vs baseline: 1.2249x; 1.2249x over previous
//
#include <hip/hip_runtime.h>
#include <hip/hip_bf16.h>

// Problem constants
#define H_ 8
#define D_ 512
#define DK_ 64
#define B_ 16
#define N_ 8192
#define M_ (B_ * N_)  // 131072 rows

typedef __attribute__((ext_vector_type(8))) short short8;
typedef __attribute__((ext_vector_type(4))) float floatx4;

// ---------------------------------------------------------------- helpers
__device__ __forceinline__ void glds16(const void* g, void* l) {
    // 16B-wide direct global->LDS DMA. LDS dest = wave-uniform base + lane*16.
    __builtin_amdgcn_global_load_lds((const __attribute__((address_space(1))) void*)g,
                                     (__attribute__((address_space(3))) void*)l,
                                     16, 0, 0);
}

__device__ __forceinline__ unsigned short f2bf(float f) {  // round-half-up
    return (unsigned short)((__float_as_uint(f) + 0x8000u) >> 16);
}

// pack two fp32 -> two bf16: low16 = bf(x), high16 = bf(y)
__device__ __forceinline__ unsigned pack_bf2(float x, float y) {
    return __builtin_amdgcn_perm(__float_as_uint(y) + 0x8000u,
                                 __float_as_uint(x) + 0x8000u, 0x07060302u);
}

__device__ __forceinline__ short8 pack_bf8(float4 lo, float4 hi) {
    union { unsigned u[4]; short8 s; } tmp;
    tmp.u[0] = pack_bf2(lo.x, lo.y);
    tmp.u[1] = pack_bf2(lo.z, lo.w);
    tmp.u[2] = pack_bf2(hi.x, hi.y);
    tmp.u[3] = pack_bf2(hi.z, hi.w);
    return tmp.s;
}

// ---------------------------------------------------------------- kernel 0a: weights fp32 -> bf16 (row-major, 1 MB)
__global__ __launch_bounds__(256) void cvt2_kernel(const float* __restrict__ s0,
                                                   const float* __restrict__ s1,
                                                   unsigned short* __restrict__ d0,
                                                   unsigned short* __restrict__ d1) {
    const int blk = blockIdx.x;
    const float* src = (blk < 256) ? s0 : s1;
    unsigned short* dst = (blk < 256) ? d0 : d1;
    int i = (blk & 255) * 256 + threadIdx.x;  // 65536 float4 per matrix
    float4 v = ((const float4*)src)[i];
    ushort4 o;
    o.x = f2bf(v.x); o.y = f2bf(v.y); o.z = f2bf(v.z); o.w = f2bf(v.w);
    ((ushort4*)dst)[i] = o;
}

// ---------------------------------------------------------------- kernel 0b: x fp32 -> bf16 in MFMA-fragment-major order
// xb chunk cid = (mt*16 + kt)*64 + lane holds x[mt*16 + (lane&15)][kt*32 + (lane>>4)*8 .. +8]
// so a GEMM A-fragment load is ONE coalesced global_load_dwordx4 per 16x32 tile.
__global__ __launch_bounds__(256) void cvt_frag_kernel(const float* __restrict__ x,
                                                       unsigned short* __restrict__ xb) {
    const int cid = blockIdx.x * 256 + threadIdx.x;  // 0..8388607
    const int lane = cid & 63;
    const int kt = (cid >> 6) & 15;
    const int mt = cid >> 10;
    const size_t src = (size_t)(mt * 16 + (lane & 15)) * 512 + kt * 32 + (lane >> 4) * 8;
    float4 f0 = *(const float4*)(x + src);
    float4 f1 = *(const float4*)(x + src + 4);
    *(short8*)(xb + (size_t)cid * 8) = pack_bf8(f0, f1);
}

// ---------------------------------------------------------------- kernel 1: W-stationary fused double-GEMM + gate + query-dot
// Block = (head h, 256-row chunk). 4 waves x 64 rows x 64 cols x 2 gemms.
// W_k[h]/W_g[h] staged frag-major in LDS via glds16 in 2 K-phases -> only 3
// barriers per block; K-loop is barrier-free. A frags: single coalesced
// global loads from frag-major xb (L2-served, 8 head-siblings per XCD).
// All LDS traffic is contiguous-1KB-per-wave (2-way bank = free).
__global__ __launch_bounds__(256, 2) void gemm_score_kernel(
    const unsigned short* __restrict__ xb,   // frag-major bf16 x
    const unsigned short* __restrict__ wkb,  // (512,512) bf16 row-major
    const unsigned short* __restrict__ wgb,  // (512,512) bf16 row-major
    const float* __restrict__ query,         // (8, 64) fp32
    float* __restrict__ s_buf)               // (B_, H_, N_) fp32
{
    __shared__ unsigned short ldsB[2][8][4][512];  // [gemm][kt][ni][lane*8] = 64 KB

    const int t = threadIdx.x;
    const int lane = t & 63;
    const int wave = t >> 6;

    // XCD remap: 8 head-siblings of one m-chunk land on one XCD (ids 8 apart)
    const int g = blockIdx.x;              // 0..4095
    const int xcd = g & 7;
    const int s = g >> 3;                  // 0..511
    const int h = s & 7;                   // head
    const int mc = ((s >> 3) << 3) | xcd;  // 0..511
    const int m0 = mc * 256;
    const int mtw = mc * 16 + wave * 4;    // wave's first 16-row tile

    floatx4 acc_k[4][4], acc_g[4][4];
#pragma unroll
    for (int i = 0; i < 4; ++i)
#pragma unroll
        for (int j = 0; j < 4; ++j) { acc_k[i][j] = (floatx4)0.f; acc_g[i][j] = (floatx4)0.f; }

    const int fr = lane & 15;
    const int q  = lane >> 4;

    for (int ph = 0; ph < 2; ++ph) {
        if (ph) __syncthreads();  // all reads of phase-0 LDS done
        // ---- stage W half (K=256) frag-major via DMA: 8 i-steps x 2 gemms.
        // For i-step: kt = i-chunk>>8, ni = (>>6)&3 are wave-uniform; lane scatter
        // is on the SOURCE side only (legal); LDS dest = uniform + lane*16.
#pragma unroll
        for (int i = 0; i < 8; ++i) {
            int j = i * 256 + t;
            int kt = j >> 8, ni = (j >> 6) & 3, ln = j & 63;
            int so = (h * 64 + ni * 16 + (ln & 15)) * 512 + ph * 256 + kt * 32 + (ln >> 4) * 8;
            glds16(wkb + so, &ldsB[0][kt][ni][ln * 8]);
            glds16(wgb + so, &ldsB[1][kt][ni][ln * 8]);
        }
        __syncthreads();

        // ---- barrier-free K-loop: 8 x K=32
#pragma unroll
        for (int kt = 0; kt < 8; ++kt) {
            const int ktg = ph * 8 + kt;
            short8 a[4], bk[4], bg[4];
#pragma unroll
            for (int mi = 0; mi < 4; ++mi)
                a[mi] = *(const short8*)(xb + ((size_t)((mtw + mi) * 16 + ktg) * 512) + lane * 8);
#pragma unroll
            for (int ni = 0; ni < 4; ++ni) {
                bk[ni] = *(const short8*)&ldsB[0][kt][ni][lane * 8];
                bg[ni] = *(const short8*)&ldsB[1][kt][ni][lane * 8];
            }
#pragma unroll
            for (int mi = 0; mi < 4; ++mi)
#pragma unroll
                for (int ni = 0; ni < 4; ++ni) {
                    acc_k[mi][ni] = __builtin_amdgcn_mfma_f32_16x16x32_bf16(a[mi], bk[ni], acc_k[mi][ni], 0, 0, 0);
                    acc_g[mi][ni] = __builtin_amdgcn_mfma_f32_16x16x32_bf16(a[mi], bg[ni], acc_g[mi][ni], 0, 0, 0);
                }
        }
    }

    // Epilogue: gated = tanh(K)*sigmoid(G); score = q . gated over 64 dk.
    // C/D layout: col = lane&15 (dk), row = q*4 + reg (m). Waves own disjoint rows.
    float qv[4];
#pragma unroll
    for (int ni = 0; ni < 4; ++ni) qv[ni] = query[h * 64 + ni * 16 + fr];

#pragma unroll
    for (int mi = 0; mi < 4; ++mi) {
#pragma unroll
        for (int r = 0; r < 4; ++r) {
            float v = 0.f;
#pragma unroll
            for (int ni = 0; ni < 4; ++ni) {
                float kv = acc_k[mi][ni][r];
                float gv = acc_g[mi][ni][r];
                float e2k = __expf(2.f * kv);
                float th = 1.f - 2.f / (e2k + 1.f);       // tanh, overflow-safe
                float sg = 1.f / (1.f + __expf(-gv));     // sigmoid
                v += qv[ni] * th * sg;
            }
            v += __shfl_xor(v, 1);
            v += __shfl_xor(v, 2);
            v += __shfl_xor(v, 4);
            v += __shfl_xor(v, 8);
            if (fr == 0) {
                int mg = m0 + wave * 64 + mi * 16 + q * 4 + r;
                int b = mg >> 13, n = mg & 8191;
                s_buf[((size_t)(b * 8 + h) << 13) + n] = v;
            }
        }
    }
}

// ---------------------------------------------------------------- kernel 2: per-(b,h) softmax stats
__global__ __launch_bounds__(256) void stats_kernel(const float* __restrict__ s_buf,
                                                    float* __restrict__ mb, float* __restrict__ lb) {
    const int bh = blockIdx.x;  // 0..127
    const float* s = s_buf + ((size_t)bh << 13);
    const int t = threadIdx.x;
    float mx = -3.0e38f;
    for (int i = t; i < 8192; i += 256) mx = fmaxf(mx, s[i]);
#pragma unroll
    for (int m = 32; m > 0; m >>= 1) mx = fmaxf(mx, __shfl_xor(mx, m));
    __shared__ float red[8];
    if ((t & 63) == 0) red[t >> 6] = mx;
    __syncthreads();
    mx = fmaxf(fmaxf(red[0], red[1]), fmaxf(red[2], red[3]));
    float sum = 0.f;
    for (int i = t; i < 8192; i += 256) sum += __expf(s[i] - mx);
#pragma unroll
    for (int m = 32; m > 0; m >>= 1) sum += __shfl_xor(sum, m);
    if ((t & 63) == 0) red[4 + (t >> 6)] = sum;
    __syncthreads();
    if (t == 0) { mb[bh] = mx; lb[bh] = red[4] + red[5] + red[6] + red[7]; }
}

// ---------------------------------------------------------------- kernel 3a: partial weighted sums (LDS-combined, 1 row/block)
__global__ __launch_bounds__(256) void out_part_kernel(
    const float* __restrict__ x, const float* __restrict__ s_buf,
    const float* __restrict__ mb, const float* __restrict__ lb,
    float* __restrict__ part) {
    const int b = blockIdx.x >> 5;      // 16
    const int chunk = blockIdx.x & 31;  // 32 chunks of 256 rows
    const int n0 = chunk * 256;
    const int t = threadIdx.x;
    __shared__ float w[2048];
    __shared__ float red2[64 * 3 * 8];  // rg 1..3 partials
    for (int i = t; i < 2048; i += 256) {
        int hh = i >> 8, nn = i & 255;
        int bh = b * 8 + hh;
        w[i] = __expf(s_buf[((size_t)bh << 13) + n0 + nn] - mb[bh]) / lb[bh];
    }
    __syncthreads();
    const int rg = t >> 6;            // 4 row-groups (disjoint rows)
    const int d0 = (t & 63) * 8;      // 8 fp32 per thread -> full 512-wide row per wave
    const float* wh = w + ((d0 >> 6) << 8);
    float acc[8] = {0.f, 0.f, 0.f, 0.f, 0.f, 0.f, 0.f, 0.f};
    for (int nn = rg; nn < 256; nn += 4) {
        const float4* row = (const float4*)(x + (((size_t)(b * 8192 + n0 + nn)) << 9) + d0);
        float4 v0 = row[0];
        float4 v1 = row[1];
        float ww = wh[nn];
        acc[0] += ww * v0.x; acc[1] += ww * v0.y;
        acc[2] += ww * v0.z; acc[3] += ww * v0.w;
        acc[4] += ww * v1.x; acc[5] += ww * v1.y;
        acc[6] += ww * v1.z; acc[7] += ww * v1.w;
    }
    if (rg) {
        float* dst = &red2[((t & 63) * 3 + (rg - 1)) * 8];
#pragma unroll
        for (int j = 0; j < 8; ++j) dst[j] = acc[j];
    }
    __syncthreads();
    if (rg == 0) {
#pragma unroll
        for (int p = 0; p < 3; ++p)
#pragma unroll
            for (int j = 0; j < 8; ++j) acc[j] += red2[((t & 63) * 3 + p) * 8 + j];
        float* dst = part + (size_t)blockIdx.x * 512 + d0;
        *(float4*)(dst)     = make_float4(acc[0], acc[1], acc[2], acc[3]);
        *(float4*)(dst + 4) = make_float4(acc[4], acc[5], acc[6], acc[7]);
    }
}

// ---------------------------------------------------------------- kernel 3b: reduce partials -> out
__global__ __launch_bounds__(512) void out_reduce_kernel(const float* __restrict__ part,
                                                         float* __restrict__ out) {
    const int b = blockIdx.x;   // 16
    const int d = threadIdx.x;  // 512
    float s = 0.f;
    const float* p = part + (size_t)b * 32 * 512 + d;
    for (int i = 0; i < 32; ++i) s += p[(size_t)i * 512];
    out[b * 512 + d] = s;
}

// ---------------------------------------------------------------- launch
extern "C" void kernel_launch(void* const* d_in, const int* in_sizes, int n_in,
                              void* d_out, int out_size, void* d_ws, size_t ws_size,
                              hipStream_t stream) {
    const float* x  = (const float*)d_in[0];
    const float* Wk = (const float*)d_in[1];
    const float* Wg = (const float*)d_in[2];
    const float* q  = (const float*)d_in[3];
    float* out = (float*)d_out;

    // ws layout (139.46 MB total — same footprint R1 ran with successfully)
    char* ws = (char*)d_ws;
    unsigned short* xb = (unsigned short*)ws;                    // 134217728 B
    float* s_buf = (float*)(ws + 134217728ull);                  // 4194304 B
    float* part  = (float*)(ws + 138412032ull);                  // 1048576 B
    unsigned short* wkb = (unsigned short*)(ws + 139460608ull);  // 524288 B
    unsigned short* wgb = (unsigned short*)(ws + 139984896ull);  // 524288 B
    float* mb = (float*)(ws + 140509184ull);                     // 512 B
    float* lb = (float*)(ws + 140509696ull);                     // 512 B

    hipLaunchKernelGGL(cvt2_kernel, dim3(512), dim3(256), 0, stream, Wk, Wg, wkb, wgb);
    hipLaunchKernelGGL(cvt_frag_kernel, dim3(32768), dim3(256), 0, stream, x, xb);
    hipLaunchKernelGGL(gemm_score_kernel, dim3(4096), dim3(256), 0, stream, xb, wkb, wgb, q, s_buf);
    hipLaunchKernelGGL(stats_kernel, dim3(128), dim3(256), 0, stream, s_buf, mb, lb);
    hipLaunchKernelGGL(out_part_kernel, dim3(512), dim3(256), 0, stream, x, s_buf, mb, lb, part);
    hipLaunchKernelGGL(out_reduce_kernel, dim3(16), dim3(512), 0, stream, part, out);
}